// Round 7
// baseline (876.905 us; speedup 1.0000x reference)
//
#include <hip/hip_runtime.h>
#include <hip/hip_bf16.h>
#include <float.h>
#include <stdint.h>

typedef __attribute__((ext_vector_type(8))) short bf16x8;
typedef __attribute__((ext_vector_type(4))) float f32x4;

#define NCH 320      // A*K = 5*64 output channels of GEMM1
#define NCG 20       // 320 / 16 channel-groups
#define GEMM_GRID 1024

static __device__ __forceinline__ unsigned short f2bf(float f) {
    union { float f; unsigned int u; } v; v.f = f;
    unsigned int u = v.u;
    u += 0x7FFFu + ((u >> 16) & 1u);   // RNE
    return (unsigned short)(u >> 16);
}

// ---- K0a: seg_start[b] = lower_bound(batch, b) ------------------------------
__global__ void seg_start_kernel(const int* __restrict__ batch,
                                 int* __restrict__ seg, int n, int b_gr) {
    int b = blockIdx.x * blockDim.x + threadIdx.x;
    if (b > b_gr) return;
    int lo = 0, hi = n;
    while (lo < hi) {
        int mid = (lo + hi) >> 1;
        if (batch[mid] < b) lo = mid + 1; else hi = mid;
    }
    seg[b] = lo;
}

// ---- K0b: pack W1 into bf16 B-fragment layout -------------------------------
// frag (cg, ks): lane l, elem j <- W1[k = ks*32 + (l>>4)*8 + j][c = cg*16 + (l&15)]
__global__ void pack_w1_kernel(const float* __restrict__ W1,
                               unsigned short* __restrict__ w1p) {
    int idx = blockIdx.x * blockDim.x + threadIdx.x;
    if (idx >= NCG * 8 * 64) return;
    int lane = idx & 63;
    int ks = (idx >> 6) & 7;
    int cg = idx >> 9;
    int col = cg * 16 + (lane & 15);
    int kbase = ks * 32 + (lane >> 4) * 8;
    unsigned short* dst = w1p + (size_t)idx * 8;
#pragma unroll
    for (int j = 0; j < 8; ++j)
        dst[j] = f2bf(W1[(size_t)(kbase + j) * NCH + col]);
}

// ---- K1: DENSE GEMM  h^T[320][npad] (fp32) = (x @ W1)^T ---------------------
// 512 thr / 8 waves. Wave w: cgs {w, w+8} on all rows, plus std cg 16+(w&3)
// on the row-half p == w>>2 (waves w and w+4 jointly cover all 4 tiles).
// All 20 cgs covered. B fragments register-pinned (96 VGPR).
__global__ __launch_bounds__(512)
__attribute__((amdgpu_waves_per_eu(2)))
void gemm_h_kernel(const float* __restrict__ x,
                   const unsigned short* __restrict__ w1p,
                   float* __restrict__ hT, int n, int nchunks, int span, int npad) {
    __shared__ unsigned short xs[64 * 256];   // 32 KB, XOR-swizzled bf16

    const int tid = threadIdx.x;
    const int lane = tid & 63;
    const int w = tid >> 6;          // 0..7
    const int rg = lane >> 4;
    const int col = lane & 15;
    const int chA = w * 16 + col;          // cgs 0..7
    const int chB = (w + 8) * 16 + col;    // cgs 8..15
    const int chS = (16 + (w & 3)) * 16 + col;  // cgs 16..19
    const int sthalf = w >> 2;             // which pass this wave does std on

    // persistent B fragments (3 cgs x 8 ks = 96 VGPR), pinned vs remat
    const bf16x8* wp = (const bf16x8*)w1p;
    bf16x8 B0[8], B1[8], Bs[8];
#pragma unroll
    for (int ks = 0; ks < 8; ++ks) {
        B0[ks] = wp[(w * 8 + ks) * 64 + lane];
        B1[ks] = wp[((w + 8) * 8 + ks) * 64 + lane];
        Bs[ks] = wp[((16 + (w & 3)) * 8 + ks) * 64 + lane];
        asm volatile("" : "+v"(B0[ks]));
        asm volatile("" : "+v"(B1[ks]));
        asm volatile("" : "+v"(Bs[ks]));
    }

    // swizzled LDS read offsets (tile 0; tile+1 adds 8192, pass adds 16384)
    int addrk[8];
#pragma unroll
    for (int ks = 0; ks < 8; ++ks)
        addrk[ks] = ((col * 512) + (rg * 16) + ks * 64) ^ ((col & 7) << 4);

    const int c0 = blockIdx.x * span;
    const int c1 = min(c0 + span, nchunks);

    for (int ch = c0; ch < c1; ++ch) {
        const int base = ch << 6;
        const int rem = min(n - base, 64);
        __syncthreads();               // previous chunk's readers done
        // ---- stage: 4 rounds, each thread converts 2 float4 -> 16 B LDS ----
        {
            const float4* xv = (const float4*)x + (size_t)base * 64;
#pragma unroll
            for (int r2 = 0; r2 < 4; ++r2) {
                int q0 = r2 * 1024 + tid * 2;      // even; q0,q0+1 same row
                int row = q0 >> 6;
                float4 v0 = make_float4(0.f, 0.f, 0.f, 0.f);
                float4 v1 = make_float4(0.f, 0.f, 0.f, 0.f);
                if (row < rem) { v0 = xv[q0]; v1 = xv[q0 + 1]; }
                __hip_bfloat162 a2 = __float22bfloat162_rn(make_float2(v0.x, v0.y));
                __hip_bfloat162 b2 = __float22bfloat162_rn(make_float2(v0.z, v0.w));
                __hip_bfloat162 c2 = __float22bfloat162_rn(make_float2(v1.x, v1.y));
                __hip_bfloat162 d2 = __float22bfloat162_rn(make_float2(v1.z, v1.w));
                uint4 pk;
                __builtin_memcpy(&pk.x, &a2, 4); __builtin_memcpy(&pk.y, &b2, 4);
                __builtin_memcpy(&pk.z, &c2, 4); __builtin_memcpy(&pk.w, &d2, 4);
                int byt = ((row * 512) + ((q0 & 63) * 8)) ^ ((row & 7) << 4);
                *(uint4*)((char*)xs + byt) = pk;
            }
        }
        __syncthreads();
        // ---- compute: 2 half-passes x 8 ks ----
#pragma unroll
        for (int p = 0; p < 2; ++p) {
            f32x4 aA0 = {0,0,0,0}, aA1 = {0,0,0,0};
            f32x4 aB0 = {0,0,0,0}, aB1 = {0,0,0,0};
            f32x4 aS0 = {0,0,0,0}, aS1 = {0,0,0,0};
            const char* pb = (const char*)xs + p * 16384;
            const bool dostd = (sthalf == p);      // wave-uniform
#pragma unroll
            for (int ks = 0; ks < 8; ++ks) {
                bf16x8 x0 = *(const bf16x8*)(pb + addrk[ks]);
                bf16x8 x1 = *(const bf16x8*)(pb + addrk[ks] + 8192);
                aA0 = __builtin_amdgcn_mfma_f32_16x16x32_bf16(x0, B0[ks], aA0, 0, 0, 0);
                aB0 = __builtin_amdgcn_mfma_f32_16x16x32_bf16(x0, B1[ks], aB0, 0, 0, 0);
                aA1 = __builtin_amdgcn_mfma_f32_16x16x32_bf16(x1, B0[ks], aA1, 0, 0, 0);
                aB1 = __builtin_amdgcn_mfma_f32_16x16x32_bf16(x1, B1[ks], aB1, 0, 0, 0);
                if (dostd) {
                    aS0 = __builtin_amdgcn_mfma_f32_16x16x32_bf16(x0, Bs[ks], aS0, 0, 0, 0);
                    aS1 = __builtin_amdgcn_mfma_f32_16x16x32_bf16(x1, Bs[ks], aS1, 0, 0, 0);
                }
            }
            // D layout: row = tile*16 + rg*4 + r, col = lane&15
            const int rb0 = base + p * 32 + rg * 4;   // tile 2p
            const int rb1 = rb0 + 16;                 // tile 2p+1
            *(f32x4*)(hT + (size_t)chA * npad + rb0) = aA0;
            *(f32x4*)(hT + (size_t)chA * npad + rb1) = aA1;
            *(f32x4*)(hT + (size_t)chB * npad + rb0) = aB0;
            *(f32x4*)(hT + (size_t)chB * npad + rb1) = aB1;
            if (dostd) {
                *(f32x4*)(hT + (size_t)chS * npad + rb0) = aS0;
                *(f32x4*)(hT + (size_t)chS * npad + rb1) = aS1;
            }
        }
    }
}

// ---- K2: segment reduce over h^T (fp32) -> z[B][320] (final values) ---------
// thread t: graph g = t % b_gr, channel c = t / b_gr. Wave = 64 consecutive
// graphs, same channel -> aggregator wave-uniform, per-lane contiguous rows.
__global__ __launch_bounds__(256) void reduce_kernel(
    const float* __restrict__ hT, const int* __restrict__ seg,
    float* __restrict__ z, int npad, int b_gr) {
    int t = blockIdx.x * 256 + threadIdx.x;
    if (t >= NCH * b_gr) return;
    int g = t % b_gr;
    int c = t / b_gr;
    int sg = seg[g], en = seg[g + 1];
    int cnt = en - sg;
    const float* p = hT + (size_t)c * npad;
    float s = 0.f, s2 = 0.f, mn = FLT_MAX, mx = -FLT_MAX;
    int r = sg;
    while ((r & 3) && r < en) {
        float v = p[r];
        s += v; s2 += v * v; mn = fminf(mn, v); mx = fmaxf(mx, v);
        ++r;
    }
    for (; r + 4 <= en; r += 4) {
        float4 u = *(const float4*)(p + r);
        s += u.x + u.y + u.z + u.w;
        s2 += u.x * u.x + u.y * u.y + u.z * u.z + u.w * u.w;
        mn = fminf(mn, fminf(fminf(u.x, u.y), fminf(u.z, u.w)));
        mx = fmaxf(mx, fmaxf(fmaxf(u.x, u.y), fmaxf(u.z, u.w)));
    }
    for (; r < en; ++r) {
        float v = p[r];
        s += v; s2 += v * v; mn = fminf(mn, v); mx = fmaxf(mx, v);
    }
    float cntf = (float)max(cnt, 1);
    int a = c >> 6;
    float res;
    if (a == 0) res = s;
    else if (a == 1) res = mn;
    else if (a == 2) res = mx;
    else if (a == 3) res = s / cntf;
    else {
        float m1 = s / cntf, m2 = s2 / cntf;
        res = sqrtf(fmaxf(m2 - m1 * m1, 1e-5f));
    }
    z[(size_t)g * NCH + c] = res;
}

// ---- K3: out = z @ W2 + b ---------------------------------------------------
__global__ __launch_bounds__(256) void k2_kernel(
    const float* __restrict__ z, const float* __restrict__ W2,
    const float* __restrict__ bias, float* __restrict__ out) {
    __shared__ float zf[NCH][17];   // +1 pad -> conflict-free transpose
    const int g0 = blockIdx.x * 16;
    const int tid = threadIdx.x;
    for (int idx = tid; idx < 16 * NCH; idx += 256) {
        int m = idx / NCH;          // graph within tile
        int c = idx - m * NCH;      // channel (fastest -> coalesced z reads)
        zf[c][m] = z[(size_t)(g0 + m) * NCH + c];
    }
    __syncthreads();
    float acc[16];
#pragma unroll
    for (int m = 0; m < 16; ++m) acc[m] = 0.f;
    for (int k = 0; k < NCH; ++k) {
        float wv = W2[(size_t)k * 256 + tid];
#pragma unroll
        for (int m = 0; m < 16; ++m) acc[m] += zf[k][m] * wv;
    }
    float bv = bias[tid];
#pragma unroll
    for (int m = 0; m < 16; ++m)
        out[(size_t)(g0 + m) * 256 + tid] = acc[m] + bv;
}

extern "C" void kernel_launch(void* const* d_in, const int* in_sizes, int n_in,
                              void* d_out, int out_size, void* d_ws, size_t ws_size,
                              hipStream_t stream) {
    const float* x = (const float*)d_in[0];
    const int* batch = (const int*)d_in[1];
    const float* W1 = (const float*)d_in[3];
    const float* W2 = (const float*)d_in[4];
    const float* bias = (const float*)d_in[5];

    const int n = in_sizes[1];           // 500000 nodes
    const int b_gr = out_size / 256;     // 8192 graphs
    const int nchunks = (n + 63) >> 6;   // 7813
    const int npad = nchunks << 6;       // 500032
    const int span = (nchunks + GEMM_GRID - 1) / GEMM_GRID;

    char* ws = (char*)d_ws;
    unsigned short* w1p = (unsigned short*)ws;               // 163840 B
    int* seg = (int*)(ws + 163840);                          // (B+1)*4
    float* z = (float*)(ws + 262144);                        // B*320*4 = 10.5 MB
    float* hT = (float*)(ws + 262144 +
                         (size_t)b_gr * NCH * sizeof(float)); // 320*npad*4 = 640 MB

    seg_start_kernel<<<(b_gr + 256) / 256, 256, 0, stream>>>(batch, seg, n, b_gr);
    pack_w1_kernel<<<(NCG * 8 * 64 + 255) / 256, 256, 0, stream>>>(W1, w1p);
    gemm_h_kernel<<<GEMM_GRID, 512, 0, stream>>>(x, w1p, hT, n, nchunks, span, npad);
    reduce_kernel<<<(NCH * b_gr + 255) / 256, 256, 0, stream>>>(hT, seg, z, npad, b_gr);
    k2_kernel<<<b_gr / 16, 256, 0, stream>>>(z, W2, bias, (float*)d_out);
}

// Round 8
// 581.419 us; speedup vs baseline: 1.5082x; 1.5082x over previous
//
#include <hip/hip_runtime.h>
#include <hip/hip_bf16.h>
#include <float.h>
#include <stdint.h>

typedef __attribute__((ext_vector_type(8))) short bf16x8;
typedef __attribute__((ext_vector_type(4))) float f32x4;

#define NCH 320      // A*K = 5*64 output channels of GEMM1
#define NCG 20       // 320 / 16 channel-groups
#define GEMM_GRID 1024
#define RT 64        // reduce row-tile

static __device__ __forceinline__ unsigned short f2bf(float f) {
    union { float f; unsigned int u; } v; v.f = f;
    unsigned int u = v.u;
    u += 0x7FFFu + ((u >> 16) & 1u);   // RNE
    return (unsigned short)(u >> 16);
}

static __device__ __forceinline__ float bf2f(unsigned short h) {
    union { unsigned int u; float f; } v; v.u = ((unsigned int)h) << 16;
    return v.f;
}

// ---- K0a: seg_start[b] = lower_bound(batch, b) ------------------------------
__global__ void seg_start_kernel(const int* __restrict__ batch,
                                 int* __restrict__ seg, int n, int b_gr) {
    int b = blockIdx.x * blockDim.x + threadIdx.x;
    if (b > b_gr) return;
    int lo = 0, hi = n;
    while (lo < hi) {
        int mid = (lo + hi) >> 1;
        if (batch[mid] < b) lo = mid + 1; else hi = mid;
    }
    seg[b] = lo;
}

// ---- K0b: pack W1 into bf16 B-fragment layout -------------------------------
// frag (cg, ks): lane l, elem j <- W1[k = ks*32 + (l>>4)*8 + j][c = cg*16 + (l&15)]
__global__ void pack_w1_kernel(const float* __restrict__ W1,
                               unsigned short* __restrict__ w1p) {
    int idx = blockIdx.x * blockDim.x + threadIdx.x;
    if (idx >= NCG * 8 * 64) return;
    int lane = idx & 63;
    int ks = (idx >> 6) & 7;
    int cg = idx >> 9;
    int col = cg * 16 + (lane & 15);
    int kbase = ks * 32 + (lane >> 4) * 8;
    unsigned short* dst = w1p + (size_t)idx * 8;
#pragma unroll
    for (int j = 0; j < 8; ++j)
        dst[j] = f2bf(W1[(size_t)(kbase + j) * NCH + col]);
}

// ---- K1: DENSE GEMM  h^T[320][npad] (bf16) = (x @ W1)^T ---------------------
// 512 thr / 8 waves. Wave w: cgs {w, w+8} on all rows, plus std cg 16+(w&3)
// on the row-half p == w>>2. B fragments register-pinned (96 VGPR).
__global__ __launch_bounds__(512)
__attribute__((amdgpu_waves_per_eu(2)))
void gemm_h_kernel(const float* __restrict__ x,
                   const unsigned short* __restrict__ w1p,
                   unsigned short* __restrict__ hT,
                   int n, int nchunks, int span, int npad) {
    __shared__ unsigned short xs[64 * 256];   // 32 KB, XOR-swizzled bf16

    const int tid = threadIdx.x;
    const int lane = tid & 63;
    const int w = tid >> 6;          // 0..7
    const int rg = lane >> 4;
    const int col = lane & 15;
    const int chA = w * 16 + col;               // cgs 0..7
    const int chB = (w + 8) * 16 + col;         // cgs 8..15
    const int chS = (16 + (w & 3)) * 16 + col;  // cgs 16..19
    const int sthalf = w >> 2;                  // std pass for this wave

    // persistent B fragments (3 cgs x 8 ks = 96 VGPR), pinned vs remat
    const bf16x8* wp = (const bf16x8*)w1p;
    bf16x8 B0[8], B1[8], Bs[8];
#pragma unroll
    for (int ks = 0; ks < 8; ++ks) {
        B0[ks] = wp[(w * 8 + ks) * 64 + lane];
        B1[ks] = wp[((w + 8) * 8 + ks) * 64 + lane];
        Bs[ks] = wp[((16 + (w & 3)) * 8 + ks) * 64 + lane];
        asm volatile("" : "+v"(B0[ks]));
        asm volatile("" : "+v"(B1[ks]));
        asm volatile("" : "+v"(Bs[ks]));
    }

    // swizzled LDS read offsets (tile 0; tile+1 adds 8192, pass adds 16384)
    int addrk[8];
#pragma unroll
    for (int ks = 0; ks < 8; ++ks)
        addrk[ks] = ((col * 512) + (rg * 16) + ks * 64) ^ ((col & 7) << 4);

    const int c0 = blockIdx.x * span;
    const int c1 = min(c0 + span, nchunks);

    for (int ch = c0; ch < c1; ++ch) {
        const int base = ch << 6;
        const int rem = min(n - base, 64);
        __syncthreads();               // previous chunk's readers done
        // ---- stage: 4 rounds, each thread converts 2 float4 -> 16 B LDS ----
        {
            const float4* xv = (const float4*)x + (size_t)base * 64;
#pragma unroll
            for (int r2 = 0; r2 < 4; ++r2) {
                int q0 = r2 * 1024 + tid * 2;      // even; q0,q0+1 same row
                int row = q0 >> 6;
                float4 v0 = make_float4(0.f, 0.f, 0.f, 0.f);
                float4 v1 = make_float4(0.f, 0.f, 0.f, 0.f);
                if (row < rem) { v0 = xv[q0]; v1 = xv[q0 + 1]; }
                __hip_bfloat162 a2 = __float22bfloat162_rn(make_float2(v0.x, v0.y));
                __hip_bfloat162 b2 = __float22bfloat162_rn(make_float2(v0.z, v0.w));
                __hip_bfloat162 c2 = __float22bfloat162_rn(make_float2(v1.x, v1.y));
                __hip_bfloat162 d2 = __float22bfloat162_rn(make_float2(v1.z, v1.w));
                uint4 pk;
                __builtin_memcpy(&pk.x, &a2, 4); __builtin_memcpy(&pk.y, &b2, 4);
                __builtin_memcpy(&pk.z, &c2, 4); __builtin_memcpy(&pk.w, &d2, 4);
                int byt = ((row * 512) + ((q0 & 63) * 8)) ^ ((row & 7) << 4);
                *(uint4*)((char*)xs + byt) = pk;
            }
        }
        __syncthreads();
        // ---- compute: 2 half-passes x 8 ks ----
#pragma unroll
        for (int p = 0; p < 2; ++p) {
            f32x4 aA0 = {0,0,0,0}, aA1 = {0,0,0,0};
            f32x4 aB0 = {0,0,0,0}, aB1 = {0,0,0,0};
            f32x4 aS0 = {0,0,0,0}, aS1 = {0,0,0,0};
            const char* pb = (const char*)xs + p * 16384;
            const bool dostd = (sthalf == p);      // wave-uniform
#pragma unroll
            for (int ks = 0; ks < 8; ++ks) {
                bf16x8 x0 = *(const bf16x8*)(pb + addrk[ks]);
                bf16x8 x1 = *(const bf16x8*)(pb + addrk[ks] + 8192);
                aA0 = __builtin_amdgcn_mfma_f32_16x16x32_bf16(x0, B0[ks], aA0, 0, 0, 0);
                aB0 = __builtin_amdgcn_mfma_f32_16x16x32_bf16(x0, B1[ks], aB0, 0, 0, 0);
                aA1 = __builtin_amdgcn_mfma_f32_16x16x32_bf16(x1, B0[ks], aA1, 0, 0, 0);
                aB1 = __builtin_amdgcn_mfma_f32_16x16x32_bf16(x1, B1[ks], aB1, 0, 0, 0);
                if (dostd) {
                    aS0 = __builtin_amdgcn_mfma_f32_16x16x32_bf16(x0, Bs[ks], aS0, 0, 0, 0);
                    aS1 = __builtin_amdgcn_mfma_f32_16x16x32_bf16(x1, Bs[ks], aS1, 0, 0, 0);
                }
            }
            // D layout: row = tile*16 + rg*4 + r, col = lane&15
            // 4 rows are contiguous in h^T[channel][row] -> 8 B bf16 store
            const int rb0 = base + p * 32 + rg * 4;   // tile 2p
            const int rb1 = rb0 + 16;                 // tile 2p+1
#define STBF(ACC, CH, RB) { \
            __hip_bfloat162 lo2 = __float22bfloat162_rn(make_float2((ACC)[0], (ACC)[1])); \
            __hip_bfloat162 hi2 = __float22bfloat162_rn(make_float2((ACC)[2], (ACC)[3])); \
            uint2 pk2; \
            __builtin_memcpy(&pk2.x, &lo2, 4); __builtin_memcpy(&pk2.y, &hi2, 4); \
            *(uint2*)(hT + (size_t)(CH) * npad + (RB)) = pk2; }
            STBF(aA0, chA, rb0)
            STBF(aA1, chA, rb1)
            STBF(aB0, chB, rb0)
            STBF(aB1, chB, rb1)
            if (dostd) {
                STBF(aS0, chS, rb0)
                STBF(aS1, chS, rb1)
            }
#undef STBF
        }
    }
}

// ---- K2: segment reduce, block-per-graph LDS transpose ----------------------
// 320 threads. Stage [rt<=64 rows][320 ch] bf16 slice into LDS with lanes ->
// rows (coalesced: 8-lane groups read 16 B runs, 8 streams/wave). Then thread
// t = channel t reduces its LDS column serially; aggregator = t>>6 is
// wave-uniform. Stats accumulate in registers across row-tiles.
__global__ __launch_bounds__(320) void reduce_kernel(
    const unsigned short* __restrict__ hT, const int* __restrict__ seg,
    float* __restrict__ z, int npad) {
    __shared__ unsigned short tile[RT][322];   // stride 161 words, ~41 KB
    const int g = blockIdx.x;
    const int sg = seg[g], en = seg[g + 1];
    const int cnt = en - sg;
    const int t = threadIdx.x;

    float s = 0.f, s2 = 0.f, mn = FLT_MAX, mx = -FLT_MAX;

    for (int r0 = 0; r0 < cnt; r0 += RT) {
        const int rt = min(cnt - r0, RT);
        __syncthreads();               // previous tile's readers done
        // load: 8 threads per channel, thread (t&7) takes rows (t&7)+8k
#pragma unroll
        for (int i = 0; i < 8; ++i) {
            int c = (t >> 3) + 40 * i;
            const unsigned short* p = hT + (size_t)c * npad + sg + r0;
            for (int j = t & 7; j < rt; j += 8)
                tile[j][c] = p[j];
        }
        __syncthreads();
        // reduce: thread t owns channel t
        for (int j = 0; j < rt; ++j) {
            float v = bf2f(tile[j][t]);
            s += v; s2 += v * v;
            mn = fminf(mn, v); mx = fmaxf(mx, v);
        }
    }

    const float cntf = (float)max(cnt, 1);
    const int a = t >> 6;              // wave-uniform aggregator id
    float res;
    if (a == 0) res = s;
    else if (a == 1) res = mn;
    else if (a == 2) res = mx;
    else if (a == 3) res = s / cntf;
    else {
        float m1 = s / cntf, m2 = s2 / cntf;
        res = sqrtf(fmaxf(m2 - m1 * m1, 1e-5f));
    }
    z[(size_t)g * NCH + t] = res;
}

// ---- K3: out = z @ W2 + b ---------------------------------------------------
__global__ __launch_bounds__(256) void k2_kernel(
    const float* __restrict__ z, const float* __restrict__ W2,
    const float* __restrict__ bias, float* __restrict__ out) {
    __shared__ float zf[NCH][17];   // +1 pad -> conflict-free transpose
    const int g0 = blockIdx.x * 16;
    const int tid = threadIdx.x;
    for (int idx = tid; idx < 16 * NCH; idx += 256) {
        int m = idx / NCH;          // graph within tile
        int c = idx - m * NCH;      // channel (fastest -> coalesced z reads)
        zf[c][m] = z[(size_t)(g0 + m) * NCH + c];
    }
    __syncthreads();
    float acc[16];
#pragma unroll
    for (int m = 0; m < 16; ++m) acc[m] = 0.f;
    for (int k = 0; k < NCH; ++k) {
        float wv = W2[(size_t)k * 256 + tid];
#pragma unroll
        for (int m = 0; m < 16; ++m) acc[m] += zf[k][m] * wv;
    }
    float bv = bias[tid];
#pragma unroll
    for (int m = 0; m < 16; ++m)
        out[(size_t)(g0 + m) * 256 + tid] = acc[m] + bv;
}

extern "C" void kernel_launch(void* const* d_in, const int* in_sizes, int n_in,
                              void* d_out, int out_size, void* d_ws, size_t ws_size,
                              hipStream_t stream) {
    const float* x = (const float*)d_in[0];
    const int* batch = (const int*)d_in[1];
    const float* W1 = (const float*)d_in[3];
    const float* W2 = (const float*)d_in[4];
    const float* bias = (const float*)d_in[5];

    const int n = in_sizes[1];           // 500000 nodes
    const int b_gr = out_size / 256;     // 8192 graphs
    const int nchunks = (n + 63) >> 6;   // 7813
    const int npad = nchunks << 6;       // 500032
    const int span = (nchunks + GEMM_GRID - 1) / GEMM_GRID;

    char* ws = (char*)d_ws;
    unsigned short* w1p = (unsigned short*)ws;               // 163840 B
    int* seg = (int*)(ws + 163840);                          // (B+1)*4
    float* z = (float*)(ws + 262144);                        // B*320*4 = 10.5 MB
    unsigned short* hT = (unsigned short*)(ws + 262144 +
                          (size_t)b_gr * NCH * sizeof(float)); // 320*npad*2 = 320 MB

    seg_start_kernel<<<(b_gr + 256) / 256, 256, 0, stream>>>(batch, seg, n, b_gr);
    pack_w1_kernel<<<(NCG * 8 * 64 + 255) / 256, 256, 0, stream>>>(W1, w1p);
    gemm_h_kernel<<<GEMM_GRID, 512, 0, stream>>>(x, w1p, hT, n, nchunks, span, npad);
    reduce_kernel<<<b_gr, 320, 0, stream>>>(hT, seg, z, npad);
    k2_kernel<<<b_gr / 16, 256, 0, stream>>>(z, W2, bias, (float*)d_out);
}

// Round 9
// 446.480 us; speedup vs baseline: 1.9640x; 1.3022x over previous
//
#include <hip/hip_runtime.h>
#include <hip/hip_bf16.h>
#include <float.h>
#include <stdint.h>

typedef __attribute__((ext_vector_type(8))) short bf16x8;
typedef __attribute__((ext_vector_type(4))) float f32x4;

#define NCH 320      // A*K = 5*64 output channels of GEMM1
#define NCG 20       // 320 / 16 channel-groups
#define GEMM_GRID 1024
#define HTS 332      // LDS h-tile row stride (shorts): rg banks {0,24,16,8}

static __device__ __forceinline__ unsigned short f2bf(float f) {
    union { float f; unsigned int u; } v; v.f = f;
    unsigned int u = v.u;
    u += 0x7FFFu + ((u >> 16) & 1u);   // RNE
    return (unsigned short)(u >> 16);
}

static __device__ __forceinline__ float bf2f(unsigned short h) {
    union { unsigned int u; float f; } v; v.u = ((unsigned int)h) << 16;
    return v.f;
}

// ---- K0a: seg_start[b] = lower_bound(batch, b) ------------------------------
__global__ void seg_start_kernel(const int* __restrict__ batch,
                                 int* __restrict__ seg, int n, int b_gr) {
    int b = blockIdx.x * blockDim.x + threadIdx.x;
    if (b > b_gr) return;
    int lo = 0, hi = n;
    while (lo < hi) {
        int mid = (lo + hi) >> 1;
        if (batch[mid] < b) lo = mid + 1; else hi = mid;
    }
    seg[b] = lo;
}

// ---- K0b: pack W1 into bf16 B-fragment layout -------------------------------
// frag (cg, ks): lane l, elem j <- W1[k = ks*32 + (l>>4)*8 + j][c = cg*16 + (l&15)]
__global__ void pack_w1_kernel(const float* __restrict__ W1,
                               unsigned short* __restrict__ w1p) {
    int idx = blockIdx.x * blockDim.x + threadIdx.x;
    if (idx >= NCG * 8 * 64) return;
    int lane = idx & 63;
    int ks = (idx >> 6) & 7;
    int cg = idx >> 9;
    int col = cg * 16 + (lane & 15);
    int kbase = ks * 32 + (lane >> 4) * 8;
    unsigned short* dst = w1p + (size_t)idx * 8;
#pragma unroll
    for (int j = 0; j < 8; ++j)
        dst[j] = f2bf(W1[(size_t)(kbase + j) * NCH + col]);
}

// ---- K1: DENSE GEMM  h[npad][320] (bf16, ROW-major) = x @ W1 ----------------
// 512 thr / 8 waves. Wave w: cgs {w, w+8} all rows + std cg 16+(w&3) on the
// row-half p == w>>2. Accs -> LDS h-tile -> coalesced global stores.
// xs double-buffered; next chunk's loads issued before compute (T14 split).
__global__ __launch_bounds__(512)
__attribute__((amdgpu_waves_per_eu(2)))
void gemm_h_kernel(const float* __restrict__ x,
                   const unsigned short* __restrict__ w1p,
                   unsigned short* __restrict__ h,
                   int n, int nchunks, int span) {
    __shared__ unsigned short xs[2][64 * 256];   // 2 x 32 KB, XOR-swizzled bf16
    __shared__ unsigned short ht[64 * HTS];      // 42.5 KB h-tile

    const int tid = threadIdx.x;
    const int lane = tid & 63;
    const int w = tid >> 6;          // 0..7
    const int rg = lane >> 4;
    const int col = lane & 15;
    const int chA = w * 16 + col;               // cgs 0..7
    const int chB = (w + 8) * 16 + col;         // cgs 8..15
    const int chS = (16 + (w & 3)) * 16 + col;  // cgs 16..19
    const int sthalf = w >> 2;                  // std pass for this wave

    // persistent B fragments (3 cgs x 8 ks = 96 VGPR), pinned vs remat
    const bf16x8* wp = (const bf16x8*)w1p;
    bf16x8 B0[8], B1[8], Bs[8];
#pragma unroll
    for (int ks = 0; ks < 8; ++ks) {
        B0[ks] = wp[(w * 8 + ks) * 64 + lane];
        B1[ks] = wp[((w + 8) * 8 + ks) * 64 + lane];
        Bs[ks] = wp[((16 + (w & 3)) * 8 + ks) * 64 + lane];
        asm volatile("" : "+v"(B0[ks]));
        asm volatile("" : "+v"(B1[ks]));
        asm volatile("" : "+v"(Bs[ks]));
    }

    // swizzled LDS read offsets (tile 0; tile+1 adds 8192, pass adds 16384)
    int addrk[8];
#pragma unroll
    for (int ks = 0; ks < 8; ++ks)
        addrk[ks] = ((col * 512) + (rg * 16) + ks * 64) ^ ((col & 7) << 4);

    const int c0 = blockIdx.x * span;
    const int c1 = min(c0 + span, nchunks);
    if (c0 >= c1) return;
    const float4* xv = (const float4*)x;

#define LD8() { const int base_ = (tc + 1) << 6; \
        const int rem_ = min(n - base_, 64); \
        const float4* xb_ = xv + (size_t)base_ * 64; \
        _Pragma("unroll") \
        for (int i_ = 0; i_ < 8; ++i_) { \
            int q_ = tid + i_ * 512; int row_ = q_ >> 6; \
            p[i_] = make_float4(0.f, 0.f, 0.f, 0.f); \
            if (row_ < rem_) p[i_] = xb_[(size_t)row_ * 64 + (q_ & 63)]; } }

#define ST8(XB) { \
        _Pragma("unroll") \
        for (int i_ = 0; i_ < 8; ++i_) { \
            int q_ = tid + i_ * 512; int row_ = q_ >> 6; \
            int byt_ = ((row_ * 512) + ((q_ & 63) * 8)) ^ ((row_ & 7) << 4); \
            __hip_bfloat162 lo2_ = __float22bfloat162_rn(make_float2(p[i_].x, p[i_].y)); \
            __hip_bfloat162 hi2_ = __float22bfloat162_rn(make_float2(p[i_].z, p[i_].w)); \
            unsigned int ulo_, uhi_; \
            __builtin_memcpy(&ulo_, &lo2_, 4); __builtin_memcpy(&uhi_, &hi2_, 4); \
            *(uint2*)((char*)(XB) + byt_) = make_uint2(ulo_, uhi_); } }

    // ---- prologue: stage chunk c0 into xs[0] ----
    {
        float4 p[8];
        int tc = c0 - 1;           // LD8 stages chunk tc+1
        LD8()
        ST8(xs[0])
    }
    __syncthreads();

    int cur = 0;
    for (int tc = c0; tc < c1; ++tc) {
        const bool more = (tc + 1 < c1);
        float4 p[8];
        if (more) LD8()            // issue next chunk's loads early
        // ---- compute chunk tc from xs[cur]; accs -> ht (bf16) ----
#pragma unroll
        for (int ps = 0; ps < 2; ++ps) {
            f32x4 aA0 = {0,0,0,0}, aA1 = {0,0,0,0};
            f32x4 aB0 = {0,0,0,0}, aB1 = {0,0,0,0};
            f32x4 aS0 = {0,0,0,0}, aS1 = {0,0,0,0};
            const char* pb = (const char*)xs[cur] + ps * 16384;
            const bool dostd = (sthalf == ps);   // wave-uniform
#pragma unroll
            for (int ks = 0; ks < 8; ++ks) {
                bf16x8 x0 = *(const bf16x8*)(pb + addrk[ks]);
                bf16x8 x1 = *(const bf16x8*)(pb + addrk[ks] + 8192);
                aA0 = __builtin_amdgcn_mfma_f32_16x16x32_bf16(x0, B0[ks], aA0, 0, 0, 0);
                aB0 = __builtin_amdgcn_mfma_f32_16x16x32_bf16(x0, B1[ks], aB0, 0, 0, 0);
                aA1 = __builtin_amdgcn_mfma_f32_16x16x32_bf16(x1, B0[ks], aA1, 0, 0, 0);
                aB1 = __builtin_amdgcn_mfma_f32_16x16x32_bf16(x1, B1[ks], aB1, 0, 0, 0);
                if (dostd) {
                    aS0 = __builtin_amdgcn_mfma_f32_16x16x32_bf16(x0, Bs[ks], aS0, 0, 0, 0);
                    aS1 = __builtin_amdgcn_mfma_f32_16x16x32_bf16(x1, Bs[ks], aS1, 0, 0, 0);
                }
            }
            // D layout: tile-row tr = ps*32 + tile16*16 + rg*4 + r, col lane&15
            const int tr0 = ps * 32 + rg * 4;     // tile 2ps
            const int tr1 = tr0 + 16;             // tile 2ps+1
#define STLDS(ACC, CH, TR) { int a_ = (TR) * HTS + (CH); \
            ht[a_] = f2bf((ACC)[0]); \
            ht[a_ + HTS] = f2bf((ACC)[1]); \
            ht[a_ + 2 * HTS] = f2bf((ACC)[2]); \
            ht[a_ + 3 * HTS] = f2bf((ACC)[3]); }
            STLDS(aA0, chA, tr0)
            STLDS(aA1, chA, tr1)
            STLDS(aB0, chB, tr0)
            STLDS(aB1, chB, tr1)
            if (dostd) {
                STLDS(aS0, chS, tr0)
                STLDS(aS1, chS, tr1)
            }
#undef STLDS
        }
        __syncthreads();           // ht complete; xs[cur] readers done
        // ---- cooperative coalesced store: ht -> h[tc*64 .. +64) ----
        {
            unsigned short* hb = h + (size_t)(tc << 6) * NCH;
#pragma unroll
            for (int i = 0; i < 10; ++i) {
                int q = tid + i * 512;           // 0..5119
                int row = q / 80;                // 80 uint2 per row
                int cid = q - row * 80;
                uint2 v = *(const uint2*)(ht + row * HTS + cid * 4);
                *(uint2*)(hb + row * NCH + cid * 4) = v;
            }
        }
        if (more) ST8(xs[cur ^ 1])
        __syncthreads();           // xs[cur^1] ready; ht readers done
        cur ^= 1;
    }
#undef LD8
#undef ST8
}

// ---- K2: segment reduce over row-major h -> z[B][320] -----------------------
// Block = one graph, 320 thr. Thread t: channels {2u, 2u+1} (u = t mod 160),
// rows of parity t/160. One uint load per row -> fully coalesced. Stats in
// registers; halves combined via tiny LDS.
__global__ __launch_bounds__(320) void reduce_kernel(
    const unsigned short* __restrict__ h, const int* __restrict__ seg,
    float* __restrict__ z) {
    __shared__ float red[160][8];
    const int g = blockIdx.x;
    const int sgr = seg[g], en = seg[g + 1];
    const int cnt = en - sgr;
    const int t = threadIdx.x;
    const int half = (t >= 160) ? 1 : 0;
    const int u = t - half * 160;

    float s0 = 0.f, q0 = 0.f, mn0 = FLT_MAX, mx0 = -FLT_MAX;
    float s1 = 0.f, q1 = 0.f, mn1 = FLT_MAX, mx1 = -FLT_MAX;
    const unsigned short* bp = h + 2 * u;
    for (int r = sgr + half; r < en; r += 2) {
        unsigned int uu = *(const unsigned int*)(bp + (size_t)r * NCH);
        float v0 = bf2f((unsigned short)(uu & 0xFFFFu));
        float v1 = bf2f((unsigned short)(uu >> 16));
        s0 += v0; q0 += v0 * v0; mn0 = fminf(mn0, v0); mx0 = fmaxf(mx0, v0);
        s1 += v1; q1 += v1 * v1; mn1 = fminf(mn1, v1); mx1 = fmaxf(mx1, v1);
    }
    if (half) {
        red[u][0] = s0; red[u][1] = q0; red[u][2] = mn0; red[u][3] = mx0;
        red[u][4] = s1; red[u][5] = q1; red[u][6] = mn1; red[u][7] = mx1;
    }
    __syncthreads();
    if (!half) {
        s0 += red[u][0]; q0 += red[u][1];
        mn0 = fminf(mn0, red[u][2]); mx0 = fmaxf(mx0, red[u][3]);
        s1 += red[u][4]; q1 += red[u][5];
        mn1 = fminf(mn1, red[u][6]); mx1 = fmaxf(mx1, red[u][7]);
        const float cntf = (float)max(cnt, 1);
        const int a = u >> 5;          // (2u)>>6: aggregator, same for both ch
        float r0, r1;
        if (a == 0) { r0 = s0; r1 = s1; }
        else if (a == 1) { r0 = mn0; r1 = mn1; }
        else if (a == 2) { r0 = mx0; r1 = mx1; }
        else if (a == 3) { r0 = s0 / cntf; r1 = s1 / cntf; }
        else {
            float m0 = s0 / cntf, m1 = s1 / cntf;
            r0 = sqrtf(fmaxf(q0 / cntf - m0 * m0, 1e-5f));
            r1 = sqrtf(fmaxf(q1 / cntf - m1 * m1, 1e-5f));
        }
        *(float2*)(z + (size_t)g * NCH + 2 * u) = make_float2(r0, r1);
    }
}

// ---- K3: out = z @ W2 + b ---------------------------------------------------
__global__ __launch_bounds__(256) void k2_kernel(
    const float* __restrict__ z, const float* __restrict__ W2,
    const float* __restrict__ bias, float* __restrict__ out) {
    __shared__ float zf[NCH][17];   // +1 pad -> conflict-free transpose
    const int g0 = blockIdx.x * 16;
    const int tid = threadIdx.x;
    for (int idx = tid; idx < 16 * NCH; idx += 256) {
        int m = idx / NCH;          // graph within tile
        int c = idx - m * NCH;      // channel (fastest -> coalesced z reads)
        zf[c][m] = z[(size_t)(g0 + m) * NCH + c];
    }
    __syncthreads();
    float acc[16];
#pragma unroll
    for (int m = 0; m < 16; ++m) acc[m] = 0.f;
    for (int k = 0; k < NCH; ++k) {
        float wv = W2[(size_t)k * 256 + tid];
#pragma unroll
        for (int m = 0; m < 16; ++m) acc[m] += zf[k][m] * wv;
    }
    float bv = bias[tid];
#pragma unroll
    for (int m = 0; m < 16; ++m)
        out[(size_t)(g0 + m) * 256 + tid] = acc[m] + bv;
}

extern "C" void kernel_launch(void* const* d_in, const int* in_sizes, int n_in,
                              void* d_out, int out_size, void* d_ws, size_t ws_size,
                              hipStream_t stream) {
    const float* x = (const float*)d_in[0];
    const int* batch = (const int*)d_in[1];
    const float* W1 = (const float*)d_in[3];
    const float* W2 = (const float*)d_in[4];
    const float* bias = (const float*)d_in[5];

    const int n = in_sizes[1];           // 500000 nodes
    const int b_gr = out_size / 256;     // 8192 graphs
    const int nchunks = (n + 63) >> 6;   // 7813
    const int span = (nchunks + GEMM_GRID - 1) / GEMM_GRID;

    char* ws = (char*)d_ws;
    unsigned short* w1p = (unsigned short*)ws;               // 160 KB
    int* seg = (int*)(ws + 163840);                          // (B+1)*4
    float* z = (float*)(ws + 262144);                        // B*320*4 = 10.5 MB
    unsigned short* h = (unsigned short*)(ws + 262144 +
                         (size_t)b_gr * NCH * sizeof(float)); // npad*320*2 = 320 MB

    seg_start_kernel<<<(b_gr + 256) / 256, 256, 0, stream>>>(batch, seg, n, b_gr);
    pack_w1_kernel<<<(NCG * 8 * 64 + 255) / 256, 256, 0, stream>>>(W1, w1p);
    gemm_h_kernel<<<GEMM_GRID, 512, 0, stream>>>(x, w1p, h, n, nchunks, span);
    reduce_kernel<<<b_gr, 320, 0, stream>>>(h, seg, z);
    k2_kernel<<<b_gr / 16, 256, 0, stream>>>(z, W2, bias, (float*)d_out);
}